// Round 4
// baseline (35507.559 us; speedup 1.0000x reference)
//
#include <hip/hip_runtime.h>

#define TPB   256
#define NBLK  256
#define UNITS 32
#define HID   1024

// 2 samples per thread: 256 blocks x 256 threads x 2 = 131072
static_assert(NBLK * TPB * 2 == 131072, "grid must cover batch exactly");

__global__ __launch_bounds__(TPB, 1)
void hopfield_rk4_f32x2(const float* __restrict__ x,  const float* __restrict__ W1,
                        const float* __restrict__ b1, const float* __restrict__ W2,
                        const float* __restrict__ b2, float* __restrict__ out) {
    // fp32 W1^T [j][u] in LDS (128 KB). Rows are 128 B; all lanes read the same
    // row (uniform addr) -> broadcast, conflict-free. W2 stays in global
    // (L2-resident, wave-uniform addresses). 4 waves/CU, 1/SIMD.
    __shared__ __align__(16) float sW1T[HID * UNITS];
    __shared__ float sb1[HID];

    const int tid = threadIdx.x;
    #pragma unroll 1
    for (int idx = tid; idx < UNITS * HID; idx += TPB) {
        int u = idx >> 10, j = idx & (HID - 1);
        sW1T[j * UNITS + u] = W1[idx];          // transpose [32][1024] -> [j][u]
    }
    #pragma unroll 1
    for (int j = tid; j < HID; j += TPB) sb1[j] = b1[j];
    __syncthreads();

    // sample A = blk*512 + tid, sample B = A + 256 (both coalesced)
    const long sA = (long)blockIdx.x * (2 * TPB) + tid;
    const long sB = sA + TPB;

    float zb[2][UNITS];
    {
        const float4* xa = (const float4*)(x + sA * UNITS);
        const float4* xb = (const float4*)(x + sB * UNITS);
        #pragma unroll
        for (int q = 0; q < 8; ++q) {
            float4 va = xa[q], vb = xb[q];
            zb[0][4*q+0] = va.x; zb[0][4*q+1] = va.y; zb[0][4*q+2] = va.z; zb[0][4*q+3] = va.w;
            zb[1][4*q+0] = vb.x; zb[1][4*q+1] = vb.y; zb[1][4*q+2] = vb.z; zb[1][4*q+3] = vb.w;
        }
    }

    const float dt = 0.1f;
    const float4* W2r = (const float4*)W2;     // row j = W2r[j*8 .. j*8+7]
    const float4* b2r = (const float4*)b2;

    #pragma unroll 1
    for (int step = 0; step < 10; ++step) {
        float acc[2][UNITS], zc[2][UNITS];
        #pragma unroll
        for (int u = 0; u < UNITS; ++u) {
            acc[0][u] = 0.f; acc[1][u] = 0.f;
            zc[0][u] = zb[0][u]; zc[1][u] = zb[1][u];
        }

        #pragma unroll 1
        for (int sub = 0; sub < 4; ++sub) {
            float yg[2][UNITS];
            #pragma unroll
            for (int u = 0; u < UNITS; ++u) { yg[0][u] = 0.f; yg[1][u] = 0.f; }

            // ---------- forward: h_j = b1_j + zc.W1col_j ; y += relu(h_j)*W2row_j ----------
            #pragma unroll 1
            for (int j = 0; j < HID; ++j) {
                const float4* w1r = (const float4*)(sW1T + j * UNITS);
                float4 wr[8];
                #pragma unroll
                for (int q = 0; q < 8; ++q) wr[q] = w1r[q];

                float bj = sb1[j];
                float pa0 = bj, pa1 = 0.f, pa2 = 0.f, pa3 = 0.f;
                float pb0 = bj, pb1 = 0.f, pb2 = 0.f, pb3 = 0.f;
                #pragma unroll
                for (int q = 0; q < 8; ++q) {
                    pa0 = fmaf(zc[0][4*q+0], wr[q].x, pa0);
                    pa1 = fmaf(zc[0][4*q+1], wr[q].y, pa1);
                    pa2 = fmaf(zc[0][4*q+2], wr[q].z, pa2);
                    pa3 = fmaf(zc[0][4*q+3], wr[q].w, pa3);
                    pb0 = fmaf(zc[1][4*q+0], wr[q].x, pb0);
                    pb1 = fmaf(zc[1][4*q+1], wr[q].y, pb1);
                    pb2 = fmaf(zc[1][4*q+2], wr[q].z, pb2);
                    pb3 = fmaf(zc[1][4*q+3], wr[q].w, pb3);
                }
                float rA = fmaxf((pa0 + pa1) + (pa2 + pa3), 0.f);
                float rB = fmaxf((pb0 + pb1) + (pb2 + pb3), 0.f);

                #pragma unroll
                for (int q = 0; q < 8; ++q) {
                    float4 wv = W2r[j * 8 + q];          // uniform address
                    yg[0][4*q+0] = fmaf(rA, wv.x, yg[0][4*q+0]);
                    yg[0][4*q+1] = fmaf(rA, wv.y, yg[0][4*q+1]);
                    yg[0][4*q+2] = fmaf(rA, wv.z, yg[0][4*q+2]);
                    yg[0][4*q+3] = fmaf(rA, wv.w, yg[0][4*q+3]);
                    yg[1][4*q+0] = fmaf(rB, wv.x, yg[1][4*q+0]);
                    yg[1][4*q+1] = fmaf(rB, wv.y, yg[1][4*q+1]);
                    yg[1][4*q+2] = fmaf(rB, wv.z, yg[1][4*q+2]);
                    yg[1][4*q+3] = fmaf(rB, wv.w, yg[1][4*q+3]);
                }
            }

            // ---------- g = 8*y/||y|| (in place), per sample ----------
            #pragma unroll
            for (int s = 0; s < 2; ++s) {
                #pragma unroll
                for (int q = 0; q < 8; ++q) {
                    float4 bv = b2r[q];
                    yg[s][4*q+0] += bv.x; yg[s][4*q+1] += bv.y;
                    yg[s][4*q+2] += bv.z; yg[s][4*q+3] += bv.w;
                }
                float n0 = 0.f, n1 = 0.f, n2 = 0.f, n3 = 0.f;
                #pragma unroll
                for (int u = 0; u < UNITS; u += 4) {
                    n0 = fmaf(yg[s][u+0], yg[s][u+0], n0);
                    n1 = fmaf(yg[s][u+1], yg[s][u+1], n1);
                    n2 = fmaf(yg[s][u+2], yg[s][u+2], n2);
                    n3 = fmaf(yg[s][u+3], yg[s][u+3], n3);
                }
                float s8 = 8.0f * rsqrtf((n0 + n1) + (n2 + n3));
                #pragma unroll
                for (int u = 0; u < UNITS; ++u) yg[s][u] *= s8;
            }

            float k[2][UNITS];
            #pragma unroll
            for (int u = 0; u < UNITS; ++u) { k[0][u] = 0.f; k[1][u] = 0.f; }

            // ---------- backward: recompute h_j; gr_j = g.W2row_j ; k -= relu'(h)*gr*W1col_j ----------
            #pragma unroll 1
            for (int j = 0; j < HID; ++j) {
                const float4* w1r = (const float4*)(sW1T + j * UNITS);
                float4 wr[8];
                #pragma unroll
                for (int q = 0; q < 8; ++q) wr[q] = w1r[q];

                float bj = sb1[j];
                float pa0 = bj, pa1 = 0.f, pa2 = 0.f, pa3 = 0.f;
                float pb0 = bj, pb1 = 0.f, pb2 = 0.f, pb3 = 0.f;
                float qa0 = 0.f, qa1 = 0.f, qa2 = 0.f, qa3 = 0.f;
                float qb0 = 0.f, qb1 = 0.f, qb2 = 0.f, qb3 = 0.f;
                #pragma unroll
                for (int q = 0; q < 8; ++q) {
                    float4 wv = W2r[j * 8 + q];          // uniform address
                    pa0 = fmaf(zc[0][4*q+0], wr[q].x, pa0);
                    pa1 = fmaf(zc[0][4*q+1], wr[q].y, pa1);
                    pa2 = fmaf(zc[0][4*q+2], wr[q].z, pa2);
                    pa3 = fmaf(zc[0][4*q+3], wr[q].w, pa3);
                    pb0 = fmaf(zc[1][4*q+0], wr[q].x, pb0);
                    pb1 = fmaf(zc[1][4*q+1], wr[q].y, pb1);
                    pb2 = fmaf(zc[1][4*q+2], wr[q].z, pb2);
                    pb3 = fmaf(zc[1][4*q+3], wr[q].w, pb3);
                    qa0 = fmaf(yg[0][4*q+0], wv.x, qa0);
                    qa1 = fmaf(yg[0][4*q+1], wv.y, qa1);
                    qa2 = fmaf(yg[0][4*q+2], wv.z, qa2);
                    qa3 = fmaf(yg[0][4*q+3], wv.w, qa3);
                    qb0 = fmaf(yg[1][4*q+0], wv.x, qb0);
                    qb1 = fmaf(yg[1][4*q+1], wv.y, qb1);
                    qb2 = fmaf(yg[1][4*q+2], wv.z, qb2);
                    qb3 = fmaf(yg[1][4*q+3], wv.w, qb3);
                }
                float hA  = (pa0 + pa1) + (pa2 + pa3);
                float hB  = (pb0 + pb1) + (pb2 + pb3);
                float grA = (qa0 + qa1) + (qa2 + qa3);
                float grB = (qb0 + qb1) + (qb2 + qb3);
                float ghA = (hA > 0.f) ? -grA : 0.f;   // pvf = -grad; relu' at 0 = 0
                float ghB = (hB > 0.f) ? -grB : 0.f;

                #pragma unroll
                for (int q = 0; q < 8; ++q) {
                    k[0][4*q+0] = fmaf(ghA, wr[q].x, k[0][4*q+0]);
                    k[0][4*q+1] = fmaf(ghA, wr[q].y, k[0][4*q+1]);
                    k[0][4*q+2] = fmaf(ghA, wr[q].z, k[0][4*q+2]);
                    k[0][4*q+3] = fmaf(ghA, wr[q].w, k[0][4*q+3]);
                    k[1][4*q+0] = fmaf(ghB, wr[q].x, k[1][4*q+0]);
                    k[1][4*q+1] = fmaf(ghB, wr[q].y, k[1][4*q+1]);
                    k[1][4*q+2] = fmaf(ghB, wr[q].z, k[1][4*q+2]);
                    k[1][4*q+3] = fmaf(ghB, wr[q].w, k[1][4*q+3]);
                }
            }

            // ---------- RK4 bookkeeping ----------
            float aw = (sub == 0 || sub == 3) ? 1.f : 2.f;
            #pragma unroll
            for (int u = 0; u < UNITS; ++u) {
                acc[0][u] += aw * k[0][u];
                acc[1][u] += aw * k[1][u];
            }
            if (sub < 3) {
                float cw = (sub == 2) ? dt : 0.5f * dt;
                #pragma unroll
                for (int u = 0; u < UNITS; ++u) {
                    zc[0][u] = fmaf(cw, k[0][u], zb[0][u]);
                    zc[1][u] = fmaf(cw, k[1][u], zb[1][u]);
                }
            }
        }

        #pragma unroll
        for (int u = 0; u < UNITS; ++u) {
            zb[0][u] = fmaf(dt * (1.f / 6.f), acc[0][u], zb[0][u]);
            zb[1][u] = fmaf(dt * (1.f / 6.f), acc[1][u], zb[1][u]);
        }
    }

    float4* oa = (float4*)(out + sA * UNITS);
    float4* ob = (float4*)(out + sB * UNITS);
    #pragma unroll
    for (int q = 0; q < 8; ++q) {
        float4 va, vb;
        va.x = zb[0][4*q+0]; va.y = zb[0][4*q+1]; va.z = zb[0][4*q+2]; va.w = zb[0][4*q+3];
        vb.x = zb[1][4*q+0]; vb.y = zb[1][4*q+1]; vb.z = zb[1][4*q+2]; vb.w = zb[1][4*q+3];
        oa[q] = va;
        ob[q] = vb;
    }
}

extern "C" void kernel_launch(void* const* d_in, const int* in_sizes, int n_in,
                              void* d_out, int out_size, void* d_ws, size_t ws_size,
                              hipStream_t stream) {
    const float* x  = (const float*)d_in[0];
    const float* W1 = (const float*)d_in[1];
    const float* b1 = (const float*)d_in[2];
    const float* W2 = (const float*)d_in[3];
    const float* b2 = (const float*)d_in[4];
    float* out = (float*)d_out;
    hipLaunchKernelGGL(hopfield_rk4_f32x2, dim3(NBLK), dim3(TPB), 0, stream,
                       x, W1, b1, W2, b2, out);
}